// Round 10
// baseline (304.908 us; speedup 1.0000x reference)
//
#include <hip/hip_runtime.h>
#include <math.h>

#define B_   8
#define C_   128
#define T_   64
#define N_   256
#define NSEQ 8

typedef __attribute__((ext_vector_type(8))) short bf16x8;
typedef __attribute__((ext_vector_type(4))) float f32x4;
typedef unsigned short ushort_t;

#define LOG2E 1.4426950408889634f
#define LN2   0.6931471805599453f

// ---- LDS word layout (26496 words = 105984 B, one 1024-thread block/CU) ----
#define R0   0       // [64][132] u32/f32: f32 x -> packed XC -> packed Y
#define R1   8448    // [128][67] f32: silu(z), [d][t]
#define RXD  17024   // [64][20] f32: x_dbl: f 0..7 row-major, then B0 C0 B1 C1 ...
#define RHP  18304   // [64][128] u32: packed split-bf16 H (kpos-swizzled image)
#define LDSW 26496

#define SELH 0x05040100u
#define SELL 0x07060302u

// ---------------- helpers ----------------------------------------------------
__device__ __forceinline__ unsigned bfhi(float x) {  // RNE f32->bf16 (as u32)
  unsigned u = __float_as_uint(x);
  return (u + 0x7FFF + ((u >> 16) & 1)) >> 16;
}
__device__ __forceinline__ unsigned packsplit(float x) {  // (lo<<16)|hi
  unsigned hi = bfhi(x);
  float rem = x - __uint_as_float(hi << 16);
  unsigned lo = bfhi(rem);
  return (hi & 0xFFFFu) | (lo << 16);
}
__device__ __forceinline__ float unpacksplit(unsigned u) {
  return __uint_as_float(u << 16) + __uint_as_float(u & 0xFFFF0000u);
}
__device__ __forceinline__ float fsilu(float v) {
  return v * __builtin_amdgcn_rcpf(1.0f + __builtin_amdgcn_exp2f(-LOG2E * v));
}
__device__ __forceinline__ float qsum4(float v) {  // sum over lane quads (DPP)
  int x = __builtin_amdgcn_update_dpp(0, __float_as_int(v), 0xB1, 0xF, 0xF, true);
  v += __int_as_float(x);
  x = __builtin_amdgcn_update_dpp(0, __float_as_int(v), 0x4E, 0xF, 0xF, true);
  v += __int_as_float(x);
  return v;
}
template <int SI>
__device__ __forceinline__ float qbcast(float v) {  // broadcast quad-lane SI
  constexpr int sel = SI | (SI << 2) | (SI << 4) | (SI << 6);
  return __int_as_float(__builtin_amdgcn_update_dpp(0, __float_as_int(v), sel, 0xF, 0xF, true));
}
// k-quad permutation: sigma = 0,4,1,5,2,6,3,7 -> bank-uniform b128 reads
__device__ __forceinline__ int sigq(int qk) { return (qk >> 1) | ((qk & 1) << 2); }
__device__ __forceinline__ int kpos(int k, int s) {  // word offset of elem k in row
  return (k & ~31) + ((((sigq((k >> 2) & 7)) + s) & 7) << 2) + (k & 3);
}
union BU { uint4 q; bf16x8 v; unsigned u[4]; };

// ---------------- K0: pre-split weights into MFMA fragment layout -----------
__global__ __launch_bounds__(512) void k_wsplit(const float* __restrict__ Win,
                                                const float* __restrict__ Wout,
                                                const float* __restrict__ Wx,
                                                ushort_t* __restrict__ wsi,
                                                ushort_t* __restrict__ wso,
                                                ushort_t* __restrict__ wsx) {
  int idx = blockIdx.x * 512 + threadIdx.x;
  const float* src;
  ushort_t* dst;
  if (idx < 1024) {
    int row = idx >> 2, kc = idx & 3;
    src = Win + row * 128 + kc * 32;
    dst = wsi + (row * 4 + kc) * 64;
  } else if (idx < 1536) {
    int k = idx - 1024;
    int row = k >> 2, kc = k & 3;
    src = Wout + row * 128 + kc * 32;
    dst = wso + (row * 4 + kc) * 64;
  } else if (idx < 1600) {
    int k = idx - 1536;
    int row = k >> 2, kc = k & 3;
    src = Wx + row * 128 + kc * 32;
    dst = wsx + (row * 4 + kc) * 64;
  } else {
    return;
  }
  for (int g = 0; g < 4; ++g) {
    unsigned hw[4], lw[4];
#pragma unroll
    for (int e2 = 0; e2 < 4; ++e2) {
      float x0 = src[g * 8 + 2 * e2], x1 = src[g * 8 + 2 * e2 + 1];
      unsigned p0 = packsplit(x0), p1 = packsplit(x1);
      hw[e2] = (p0 & 0xFFFFu) | (p1 << 16);
      lw[e2] = (p0 >> 16) | (p1 & 0xFFFF0000u);
    }
    *(uint4*)(dst + (g * 2 + 0) * 8) = make_uint4(hw[0], hw[1], hw[2], hw[3]);
    *(uint4*)(dst + (g * 2 + 1) * 8) = make_uint4(lw[0], lw[1], lw[2], lw[3]);
  }
}

// -------- K1: LayerNorm over C + transpose + PACK to (B*N, T, kpos(C)) -----
__global__ __launch_bounds__(256) void k_ln(const float* __restrict__ x,
                                            const float* __restrict__ gam,
                                            const float* __restrict__ bet,
                                            unsigned* __restrict__ hp) {
  __shared__ float tile[128 * 36];
  __shared__ float ps[8 * 32], pq[8 * 32], mean_s[32], rstd_s[32];
  int bx = blockIdx.x;
  int nt = bx & 7, t = (bx >> 3) & 63, b = bx >> 9;
  int n0 = nt * 32;
  int tid = threadIdx.x;
  const float4* x4 = (const float4*)x;
  for (int it = 0; it < 4; ++it) {
    int idx4 = it * 256 + tid;
    int c = idx4 >> 3, nn4 = idx4 & 7;
    float4 v = x4[((b * C_ + c) * T_ + t) * (N_ / 4) + (n0 >> 2) + nn4];
    *(float4*)&tile[c * 36 + nn4 * 4] = v;
  }
  __syncthreads();
  {
    int nn = tid & 31, cg = tid >> 5;
    float s = 0.f, q = 0.f;
    for (int i = 0; i < 16; ++i) {
      float v = tile[(cg * 16 + i) * 36 + nn];
      s += v; q += v * v;
    }
    ps[cg * 32 + nn] = s; pq[cg * 32 + nn] = q;
  }
  __syncthreads();
  if (tid < 32) {
    float ss = 0.f, qq = 0.f;
    for (int g2 = 0; g2 < 8; ++g2) { ss += ps[g2 * 32 + tid]; qq += pq[g2 * 32 + tid]; }
    float mu = ss * (1.f / 128.f);
    float var = qq * (1.f / 128.f) - mu * mu;
    mean_s[tid] = mu;
    rstd_s[tid] = rsqrtf(var + 1e-5f);
  }
  __syncthreads();
  {
    int c = tid & 127, half = tid >> 7;
    float gm = gam[c], bb = bet[c];
    int kp = kpos(c, t & 7);           // swizzled word slot (t uniform per block)
    for (int it = 0; it < 16; ++it) {
      int n = it * 2 + half;
      float v = (tile[c * 36 + n] - mean_s[n]) * rstd_s[n] * gm + bb;
      hp[((b * N_ + n0 + n) * (long)T_ + t) * 128 + kp] = packsplit(v);
    }
  }
}

// ---------------- K2: fused Mamba, 1024 threads (16 waves/CU guaranteed) ----
__global__ __launch_bounds__(1024, 1) void k_mamba(
    unsigned* ws,                       // (B*N, T, 128) packed H -> y f32 in place
    const ushort_t* __restrict__ wsi,   // pre-split Win fragments
    const ushort_t* __restrict__ wso,   // pre-split Wout fragments
    const ushort_t* __restrict__ wsx,   // pre-split Wx fragments
    const float* __restrict__ convw,    // (3,1,128)
    const float* __restrict__ convb,    // (128)
    const float* __restrict__ Wdt,      // (128,8)
    const float* __restrict__ bdt,      // (128)
    const float* __restrict__ Alog,     // (128,4)
    const float* __restrict__ Dp)       // (128)
{
  extern __shared__ float L[];
  unsigned* Li = (unsigned*)L;
  int tid = threadIdx.x;
  int lane = tid & 63;
  int w = tid >> 6;                 // wave 0..15
  int r16 = lane & 15, g = lane >> 4;
  const uint4* wsi4 = (const uint4*)wsi;
  const uint4* wso4 = (const uint4*)wso;
  const uint4* wsx4 = (const uint4*)wsx;

  // ---- persistent weights: in_proj col-tile w (32), out_proj col-tile w&7 (32)
  uint4 wih[4], wil[4], woh[4], wol[4];
#pragma unroll
  for (int kc = 0; kc < 4; ++kc) {
    int cbi = ((w * 16 + r16) * 4 + kc) * 8 + g * 2;
    wih[kc] = wsi4[cbi];
    wil[kc] = wsi4[cbi + 1];
    int cbo = ((((w & 7) * 16) + r16) * 4 + kc) * 8 + g * 2;
    woh[kc] = wso4[cbo];
    wol[kc] = wso4[cbo + 1];
  }
  // ---- per-thread constants ----
  int dc = tid & 127, tq = tid >> 7;                  // conv role (8 t each)
  float cw0 = convw[dc], cw1 = convw[128 + dc], cw2 = convw[256 + dc];
  float cbv = convb[dc];
  int ds = (tid >> 2) & 127, ss = tid & 3;            // scan role (tid<512 active)
  float4 wdta = *(const float4*)&Wdt[ds * 8];
  float4 wdtb = *(const float4*)&Wdt[ds * 8 + 4];
  float bd = bdt[ds];
  float As2 = -expf(Alog[ds * 4 + ss]) * LOG2E;
  float Dd = Dp[ds];
  int kc_d = kpos(ds, 0) & ~28;                       // (ds&~31)+(ds&3)
  int qs_d = sigq((ds >> 2) & 7);

  int sA = r16 & 7;
  int slotA = (g + sA) & 7, slotB = (g + 4 + sA) & 7;

  // prefetch seq 0 H into registers
  uint4 pf0, pf1;
  {
    const uint4* s4 = (const uint4*)(ws + (size_t)blockIdx.x * NSEQ * 8192);
    pf0 = s4[tid * 2];
    pf1 = s4[tid * 2 + 1];
  }

  for (int iseq = 0; iseq < NSEQ; ++iseq) {
    size_t seqoff = ((size_t)blockIdx.x * NSEQ + iseq) * 8192;

    // ---- P0: commit prefetched packed H to LDS ----
    *(uint4*)&Li[RHP + tid * 8]     = pf0;
    *(uint4*)&Li[RHP + tid * 8 + 4] = pf1;
    __syncthreads();

    // ---- P1: in_proj xz(64x256) = H @ Win^T; wave w -> cols 16w..16w+16 ----
    f32x4 acc[4];
#pragma unroll
    for (int rt = 0; rt < 4; ++rt) acc[rt] = (f32x4){0.f, 0.f, 0.f, 0.f};
#pragma unroll
    for (int kc = 0; kc < 4; ++kc) {
      BU bh, bl;
      bh.q = wih[kc];
      bl.q = wil[kc];
#pragma unroll
      for (int rt = 0; rt < 4; ++rt) {
        int base = RHP + (rt * 16 + r16) * 128 + kc * 32;
        uint4 wa = *(const uint4*)&Li[base + slotA * 4];
        uint4 wb = *(const uint4*)&Li[base + slotB * 4];
        BU ah, al;
        ah.u[0] = __builtin_amdgcn_perm(wa.y, wa.x, SELH);
        ah.u[1] = __builtin_amdgcn_perm(wa.w, wa.z, SELH);
        ah.u[2] = __builtin_amdgcn_perm(wb.y, wb.x, SELH);
        ah.u[3] = __builtin_amdgcn_perm(wb.w, wb.z, SELH);
        al.u[0] = __builtin_amdgcn_perm(wa.y, wa.x, SELL);
        al.u[1] = __builtin_amdgcn_perm(wa.w, wa.z, SELL);
        al.u[2] = __builtin_amdgcn_perm(wb.y, wb.x, SELL);
        al.u[3] = __builtin_amdgcn_perm(wb.w, wb.z, SELL);
        acc[rt] = __builtin_amdgcn_mfma_f32_16x16x32_bf16(al.v, bh.v, acc[rt], 0, 0, 0);
        acc[rt] = __builtin_amdgcn_mfma_f32_16x16x32_bf16(ah.v, bl.v, acc[rt], 0, 0, 0);
        acc[rt] = __builtin_amdgcn_mfma_f32_16x16x32_bf16(ah.v, bh.v, acc[rt], 0, 0, 0);
      }
    }
    __syncthreads();   // H fully consumed; RHP free for next prefetch commit

    // issue next-seq H loads (register-staged; hides under P2..P6)
    if (iseq + 1 < NSEQ) {
      const uint4* s4 = (const uint4*)(ws + seqoff + 8192);
      pf0 = s4[tid * 2];
      pf1 = s4[tid * 2 + 1];
    }

    // ---- P2: scatter: waves 0-7 -> x f32 [t][132]; 8-15 -> silu(z) [d][67] ----
    if (w < 8) {
      int dl0 = w * 16;
#pragma unroll
      for (int rt = 0; rt < 4; ++rt)
#pragma unroll
        for (int r = 0; r < 4; ++r)
          L[R0 + (rt * 16 + g * 4 + r) * 132 + dl0 + r16] = acc[rt][r];
    } else {
      int d = (w - 8) * 16 + r16;
#pragma unroll
      for (int rt = 0; rt < 4; ++rt)
#pragma unroll
        for (int r = 0; r < 4; ++r)
          L[R1 + d * 67 + rt * 16 + g * 4 + r] = fsilu(acc[rt][r]);
    }
    __syncthreads();

    // ---- P3: causal conv(3) + SiLU; packed XC back into R0 (kpos slots) ----
    {
      int t0 = tq * 8;
      float xin[10];
#pragma unroll
      for (int ii = 0; ii < 10; ++ii) {
        int t = t0 - 2 + ii;
        xin[ii] = (t < 0) ? 0.f : L[R0 + t * 132 + dc];
      }
      __syncthreads();   // all pre-conv reads done before overwrite
#pragma unroll
      for (int ii = 0; ii < 8; ++ii) {
        int t = t0 + ii;
        float v = fmaf(cw2, xin[ii + 2], fmaf(cw1, xin[ii + 1], fmaf(cw0, xin[ii], cbv)));
        Li[R0 + t * 132 + kpos(dc, t & 7)] = packsplit(fsilu(v));
      }
    }
    __syncthreads();

    // ---- P4: x_proj x_dbl(64x16) = XC @ Wx^T via MFMA (waves 0-3) ----
    if (w < 4) {
      f32x4 o = (f32x4){0.f, 0.f, 0.f, 0.f};
#pragma unroll
      for (int kc = 0; kc < 4; ++kc) {
        int cb = (r16 * 4 + kc) * 8 + g * 2;
        BU bh, bl;
        bh.q = wsx4[cb];
        bl.q = wsx4[cb + 1];
        int base = R0 + (w * 16 + r16) * 132 + kc * 32;
        uint4 wa = *(const uint4*)&Li[base + slotA * 4];
        uint4 wb = *(const uint4*)&Li[base + slotB * 4];
        BU ah, al;
        ah.u[0] = __builtin_amdgcn_perm(wa.y, wa.x, SELH);
        ah.u[1] = __builtin_amdgcn_perm(wa.w, wa.z, SELH);
        ah.u[2] = __builtin_amdgcn_perm(wb.y, wb.x, SELH);
        ah.u[3] = __builtin_amdgcn_perm(wb.w, wb.z, SELH);
        al.u[0] = __builtin_amdgcn_perm(wa.y, wa.x, SELL);
        al.u[1] = __builtin_amdgcn_perm(wa.w, wa.z, SELL);
        al.u[2] = __builtin_amdgcn_perm(wb.y, wb.x, SELL);
        al.u[3] = __builtin_amdgcn_perm(wb.w, wb.z, SELL);
        o = __builtin_amdgcn_mfma_f32_16x16x32_bf16(al.v, bh.v, o, 0, 0, 0);
        o = __builtin_amdgcn_mfma_f32_16x16x32_bf16(ah.v, bl.v, o, 0, 0, 0);
        o = __builtin_amdgcn_mfma_f32_16x16x32_bf16(ah.v, bh.v, o, 0, 0, 0);
      }
      // features: dt f (0..7) row-major; B_s -> 8+2s; C_s -> 9+2s
      int p = (r16 < 8) ? r16 : (r16 < 12 ? 8 + 2 * (r16 - 8) : 9 + 2 * (r16 - 12));
#pragma unroll
      for (int q = 0; q < 4; ++q)
        L[RXD + (w * 16 + g * 4 + q) * 20 + p] = o[q];
    }
    __syncthreads();

    // ---- P5: selective scan (tid<512): dt-share, packed Y over packed XC ----
    if (tid < 512) {
      float hsv = 0.f;
#pragma unroll 2
      for (int tb = 0; tb < 16; ++tb) {
        int tme = tb * 4 + ss;                        // this lane's dt timestep
        const float* xr = &L[RXD + tme * 20];
        float4 xa = *(const float4*)xr;
        float4 xb = *(const float4*)(xr + 4);
        float dot = bd;
        dot = fmaf(xa.x, wdta.x, dot); dot = fmaf(xa.y, wdta.y, dot);
        dot = fmaf(xa.z, wdta.z, dot); dot = fmaf(xa.w, wdta.w, dot);
        dot = fmaf(xb.x, wdtb.x, dot); dot = fmaf(xb.y, wdtb.y, dot);
        dot = fmaf(xb.z, wdtb.z, dot); dot = fmaf(xb.w, wdtb.w, dot);
        float e = __builtin_amdgcn_exp2f(dot * LOG2E);
        float sp = LN2 * __builtin_amdgcn_logf(1.0f + e);
        float dtme = (dot > 20.f) ? dot : sp;         // softplus(own t)

#define SCANSTEP(SI)                                                          \
        {                                                                     \
          int t = tb * 4 + SI;                                                \
          float dtv = qbcast<SI>(dtme);                                       \
          float2 bc = *(const float2*)&L[RXD + t * 20 + 8 + 2 * ss];          \
          int xoff = R0 + t * 132 + kc_d + (((qs_d + (t & 7)) & 7) << 2);     \
          float xcv = unpacksplit(Li[xoff]);                                  \
          float dA = __builtin_amdgcn_exp2f(dtv * As2);                       \
          hsv = fmaf(hsv, dA, dtv * xcv * bc.x);                              \
          float y = qsum4(hsv * bc.y);                                        \
          if (SI == ss) {                                                     \
            y = fmaf(xcv, Dd, y);                                             \
            y *= L[R1 + ds * 67 + t];                                         \
            Li[xoff] = packsplit(y);                                          \
          }                                                                   \
        }
        SCANSTEP(0)
        SCANSTEP(1)
        SCANSTEP(2)
        SCANSTEP(3)
#undef SCANSTEP
      }
    }
    __syncthreads();

    // ---- P6: out_proj out(64x128) = Y @ Wout^T; wave pair splits rows ----
    {
      int rt0 = (w >> 3) * 2;
      int cc = (w & 7) * 16 + r16;
      f32x4 o[2];
      o[0] = (f32x4){0.f, 0.f, 0.f, 0.f};
      o[1] = (f32x4){0.f, 0.f, 0.f, 0.f};
#pragma unroll
      for (int kc = 0; kc < 4; ++kc) {
        BU bh, bl;
        bh.q = woh[kc];
        bl.q = wol[kc];
#pragma unroll
        for (int rr = 0; rr < 2; ++rr) {
          int base = R0 + ((rt0 + rr) * 16 + r16) * 132 + kc * 32;
          uint4 wa = *(const uint4*)&Li[base + slotA * 4];
          uint4 wb = *(const uint4*)&Li[base + slotB * 4];
          BU ah, al;
          ah.u[0] = __builtin_amdgcn_perm(wa.y, wa.x, SELH);
          ah.u[1] = __builtin_amdgcn_perm(wa.w, wa.z, SELH);
          ah.u[2] = __builtin_amdgcn_perm(wb.y, wb.x, SELH);
          ah.u[3] = __builtin_amdgcn_perm(wb.w, wb.z, SELH);
          al.u[0] = __builtin_amdgcn_perm(wa.y, wa.x, SELL);
          al.u[1] = __builtin_amdgcn_perm(wa.w, wa.z, SELL);
          al.u[2] = __builtin_amdgcn_perm(wb.y, wb.x, SELL);
          al.u[3] = __builtin_amdgcn_perm(wb.w, wb.z, SELL);
          o[rr] = __builtin_amdgcn_mfma_f32_16x16x32_bf16(al.v, bh.v, o[rr], 0, 0, 0);
          o[rr] = __builtin_amdgcn_mfma_f32_16x16x32_bf16(ah.v, bl.v, o[rr], 0, 0, 0);
          o[rr] = __builtin_amdgcn_mfma_f32_16x16x32_bf16(ah.v, bh.v, o[rr], 0, 0, 0);
        }
      }
      float* yout = (float*)(ws + seqoff);
#pragma unroll
      for (int rr = 0; rr < 2; ++rr)
#pragma unroll
        for (int r = 0; r < 4; ++r)
          yout[((rt0 + rr) * 16 + g * 4 + r) * C_ + cc] = o[rr][r];
    }
    __syncthreads();   // LDS reuse next sequence
  }
}

// ---------------- K3: transpose (B*N,T,C) -> (B,C,T,N) ----------------------
__global__ __launch_bounds__(256) void k_out_tr(const float* __restrict__ ws_y,
                                                float* __restrict__ out) {
  __shared__ float tile[32 * 132];
  int bx = blockIdx.x;
  int nt = bx & 7, t = (bx >> 3) & 63, b = bx >> 9;
  int n0 = nt * 32;
  int tid = threadIdx.x;
  const float4* y4 = (const float4*)ws_y;
  for (int it = 0; it < 4; ++it) {
    int idx4 = it * 256 + tid;
    int nn = idx4 >> 5, c4 = idx4 & 31;
    float4 v = y4[((b * N_ + n0 + nn) * (long)T_ + t) * (C_ / 4) + c4];
    *(float4*)&tile[nn * 132 + c4 * 4] = v;
  }
  __syncthreads();
  int nn = tid & 31, cg = tid >> 5;
  for (int i = 0; i < 16; ++i) {
    int c = cg * 16 + i;
    out[((b * C_ + c) * (long)T_ + t) * N_ + n0 + nn] = tile[nn * 132 + c];
  }
}

extern "C" void kernel_launch(void* const* d_in, const int* in_sizes, int n_in,
                              void* d_out, int out_size, void* d_ws, size_t ws_size,
                              hipStream_t stream) {
  const float* x    = (const float*)d_in[0];
  const float* gam  = (const float*)d_in[1];
  const float* bet  = (const float*)d_in[2];
  const float* Win  = (const float*)d_in[3];
  const float* cw   = (const float*)d_in[4];
  const float* cb   = (const float*)d_in[5];
  const float* Wx   = (const float*)d_in[6];
  const float* Wdt  = (const float*)d_in[7];
  const float* bdt  = (const float*)d_in[8];
  const float* Alog = (const float*)d_in[9];
  const float* Dp   = (const float*)d_in[10];
  const float* Wout = (const float*)d_in[11];
  float* out = (float*)d_out;
  unsigned* ws = (unsigned*)d_ws;  // 64 MiB: packed H image -> y f32 in place

  // split-weight storage: ws tail if it fits, else scribble d_out
  const size_t HBYTES = 67108864ull;                      // 64 MiB
  const size_t WBYTES = 131072ull + 65536ull + 8192ull;   // Win + Wout + Wx splits
  char* wtail;
  if (ws_size >= HBYTES + WBYTES) wtail = (char*)d_ws + HBYTES;
  else                            wtail = (char*)d_out;
  ushort_t* wsi = (ushort_t*)wtail;
  ushort_t* wso = (ushort_t*)(wtail + 131072);
  ushort_t* wsx = (ushort_t*)(wtail + 131072 + 65536);

  (void)hipFuncSetAttribute((const void*)k_mamba,
                            hipFuncAttributeMaxDynamicSharedMemorySize,
                            LDSW * 4);

  k_wsplit<<<4, 512, 0, stream>>>(Win, Wout, Wx, wsi, wso, wsx);
  k_ln<<<4096, 256, 0, stream>>>(x, gam, bet, ws);
  k_mamba<<<2048 / NSEQ, 1024, LDSW * 4, stream>>>(ws, wsi, wso, wsx, cw, cb,
                                                   Wdt, bdt, Alog, Dp);
  k_out_tr<<<4096, 256, 0, stream>>>((const float*)ws, out);
}

// Round 11
// 281.893 us; speedup vs baseline: 1.0816x; 1.0816x over previous
//
#include <hip/hip_runtime.h>
#include <math.h>

#define B_   8
#define C_   128
#define T_   64
#define N_   256
#define NSEQ 8

typedef __attribute__((ext_vector_type(8))) short bf16x8;
typedef __attribute__((ext_vector_type(4))) float f32x4;
typedef unsigned short ushort_t;

#define LOG2E 1.4426950408889634f
#define LN2   0.6931471805599453f

// ---- LDS word layout (26496 words = 105984 B, one 1024-thread block/CU) ----
#define R0   0       // [64][132] u32/f32: f32 x -> packed XC -> packed Y
#define R1   8448    // [128][67] f32: silu(z), [d][t]
#define RXD  17024   // [64][20] f32: x_dbl: f 0..7 row-major, then B0 C0 B1 C1 ...
#define RHP  18304   // [64][128] u32: packed split-bf16 H (kpos-swizzled image)
#define LDSW 26496

#define SELH 0x05040100u
#define SELL 0x07060302u

// ---------------- helpers ----------------------------------------------------
__device__ __forceinline__ unsigned bfhi(float x) {  // RNE f32->bf16 (as u32)
  unsigned u = __float_as_uint(x);
  return (u + 0x7FFF + ((u >> 16) & 1)) >> 16;
}
__device__ __forceinline__ unsigned packsplit(float x) {  // (lo<<16)|hi
  unsigned hi = bfhi(x);
  float rem = x - __uint_as_float(hi << 16);
  unsigned lo = bfhi(rem);
  return (hi & 0xFFFFu) | (lo << 16);
}
__device__ __forceinline__ float unpacksplit(unsigned u) {
  return __uint_as_float(u << 16) + __uint_as_float(u & 0xFFFF0000u);
}
__device__ __forceinline__ float fsilu(float v) {
  return v * __builtin_amdgcn_rcpf(1.0f + __builtin_amdgcn_exp2f(-LOG2E * v));
}
__device__ __forceinline__ float qsum4(float v) {  // sum over lane quads (DPP)
  int x = __builtin_amdgcn_update_dpp(0, __float_as_int(v), 0xB1, 0xF, 0xF, true);
  v += __int_as_float(x);
  x = __builtin_amdgcn_update_dpp(0, __float_as_int(v), 0x4E, 0xF, 0xF, true);
  v += __int_as_float(x);
  return v;
}
template <int SI>
__device__ __forceinline__ float qbcast(float v) {  // broadcast quad-lane SI
  constexpr int sel = SI | (SI << 2) | (SI << 4) | (SI << 6);
  return __int_as_float(__builtin_amdgcn_update_dpp(0, __float_as_int(v), sel, 0xF, 0xF, true));
}
// k-quad permutation: sigma = 0,4,1,5,2,6,3,7 -> bank-uniform b128 reads
__device__ __forceinline__ int sigq(int qk) { return (qk >> 1) | ((qk & 1) << 2); }
__device__ __forceinline__ int kpos(int k, int s) {  // word offset of elem k in row
  return (k & ~31) + ((((sigq((k >> 2) & 7)) + s) & 7) << 2) + (k & 3);
}
union BU { uint4 q; bf16x8 v; unsigned u[4]; };

// ---------------- K0: pre-split weights into MFMA fragment layout -----------
__global__ __launch_bounds__(512) void k_wsplit(const float* __restrict__ Win,
                                                const float* __restrict__ Wout,
                                                const float* __restrict__ Wx,
                                                ushort_t* __restrict__ wsi,
                                                ushort_t* __restrict__ wso,
                                                ushort_t* __restrict__ wsx) {
  int idx = blockIdx.x * 512 + threadIdx.x;
  const float* src;
  ushort_t* dst;
  if (idx < 1024) {
    int row = idx >> 2, kc = idx & 3;
    src = Win + row * 128 + kc * 32;
    dst = wsi + (row * 4 + kc) * 64;
  } else if (idx < 1536) {
    int k = idx - 1024;
    int row = k >> 2, kc = k & 3;
    src = Wout + row * 128 + kc * 32;
    dst = wso + (row * 4 + kc) * 64;
  } else if (idx < 1600) {
    int k = idx - 1536;
    int row = k >> 2, kc = k & 3;
    src = Wx + row * 128 + kc * 32;
    dst = wsx + (row * 4 + kc) * 64;
  } else {
    return;
  }
  for (int g = 0; g < 4; ++g) {
    unsigned hw[4], lw[4];
#pragma unroll
    for (int e2 = 0; e2 < 4; ++e2) {
      float x0 = src[g * 8 + 2 * e2], x1 = src[g * 8 + 2 * e2 + 1];
      unsigned p0 = packsplit(x0), p1 = packsplit(x1);
      hw[e2] = (p0 & 0xFFFFu) | (p1 << 16);
      lw[e2] = (p0 >> 16) | (p1 & 0xFFFF0000u);
    }
    *(uint4*)(dst + (g * 2 + 0) * 8) = make_uint4(hw[0], hw[1], hw[2], hw[3]);
    *(uint4*)(dst + (g * 2 + 1) * 8) = make_uint4(lw[0], lw[1], lw[2], lw[3]);
  }
}

// -------- K1: LayerNorm over C + transpose + PACK to (B*N, T, kpos(C)) -----
__global__ __launch_bounds__(256) void k_ln(const float* __restrict__ x,
                                            const float* __restrict__ gam,
                                            const float* __restrict__ bet,
                                            unsigned* __restrict__ hp) {
  __shared__ float tile[128 * 36];
  __shared__ float ps[8 * 32], pq[8 * 32], mean_s[32], rstd_s[32];
  int bx = blockIdx.x;
  int nt = bx & 7, t = (bx >> 3) & 63, b = bx >> 9;
  int n0 = nt * 32;
  int tid = threadIdx.x;
  const float4* x4 = (const float4*)x;
  for (int it = 0; it < 4; ++it) {
    int idx4 = it * 256 + tid;
    int c = idx4 >> 3, nn4 = idx4 & 7;
    float4 v = x4[((b * C_ + c) * T_ + t) * (N_ / 4) + (n0 >> 2) + nn4];
    *(float4*)&tile[c * 36 + nn4 * 4] = v;
  }
  __syncthreads();
  {
    int nn = tid & 31, cg = tid >> 5;
    float s = 0.f, q = 0.f;
    for (int i = 0; i < 16; ++i) {
      float v = tile[(cg * 16 + i) * 36 + nn];
      s += v; q += v * v;
    }
    ps[cg * 32 + nn] = s; pq[cg * 32 + nn] = q;
  }
  __syncthreads();
  if (tid < 32) {
    float ss = 0.f, qq = 0.f;
    for (int g2 = 0; g2 < 8; ++g2) { ss += ps[g2 * 32 + tid]; qq += pq[g2 * 32 + tid]; }
    float mu = ss * (1.f / 128.f);
    float var = qq * (1.f / 128.f) - mu * mu;
    mean_s[tid] = mu;
    rstd_s[tid] = rsqrtf(var + 1e-5f);
  }
  __syncthreads();
  {
    int c = tid & 127, half = tid >> 7;
    float gm = gam[c], bb = bet[c];
    int kp = kpos(c, t & 7);           // swizzled word slot (t uniform per block)
    for (int it = 0; it < 16; ++it) {
      int n = it * 2 + half;
      float v = (tile[c * 36 + n] - mean_s[n]) * rstd_s[n] * gm + bb;
      hp[((b * N_ + n0 + n) * (long)T_ + t) * 128 + kp] = packsplit(v);
    }
  }
}

// ---------------- K2: fused Mamba, 1024 threads, <=128 regs (no spill) ------
// Register budget at 16 waves/CU is 128 total (unified VGPR+AGPR). r10 held
// 64 weight regs persistently -> clamp+spill. Here: in_proj weights persistent
// (32), out_proj weights STREAMED once per sequence with loads issued before
// the scan phase (latency hidden under ~64 serial scan steps); an opaque asm
// offset stops LICM from re-hoisting them into persistent registers.
__global__ __launch_bounds__(1024, 1) void k_mamba(
    unsigned* ws,                       // (B*N, T, 128) packed H -> y f32 in place
    const ushort_t* __restrict__ wsi,   // pre-split Win fragments
    const ushort_t* __restrict__ wso,   // pre-split Wout fragments
    const ushort_t* __restrict__ wsx,   // pre-split Wx fragments
    const float* __restrict__ convw,    // (3,1,128)
    const float* __restrict__ convb,    // (128)
    const float* __restrict__ Wdt,      // (128,8)
    const float* __restrict__ bdt,      // (128)
    const float* __restrict__ Alog,     // (128,4)
    const float* __restrict__ Dp)       // (128)
{
  extern __shared__ float L[];
  unsigned* Li = (unsigned*)L;
  int tid = threadIdx.x;
  int lane = tid & 63;
  int w = tid >> 6;                 // wave 0..15
  int r16 = lane & 15, g = lane >> 4;
  const uint4* wsi4 = (const uint4*)wsi;
  const uint4* wso4 = (const uint4*)wso;
  const uint4* wsx4 = (const uint4*)wsx;

  // ---- persistent weights: in_proj col-tile w only (32 regs) ----
  uint4 wih[4], wil[4];
#pragma unroll
  for (int kc = 0; kc < 4; ++kc) {
    int cbi = ((w * 16 + r16) * 4 + kc) * 8 + g * 2;
    wih[kc] = wsi4[cbi];
    wil[kc] = wsi4[cbi + 1];
  }
  // ---- per-thread constants ----
  int dc = tid & 127, tq = tid >> 7;                  // conv role (8 t each)
  float cw0 = convw[dc], cw1 = convw[128 + dc], cw2 = convw[256 + dc];
  float cbv = convb[dc];
  int ds = (tid >> 2) & 127, ss = tid & 3;            // scan role (tid<512 active)
  float4 wdta = *(const float4*)&Wdt[ds * 8];
  float4 wdtb = *(const float4*)&Wdt[ds * 8 + 4];
  float bd = bdt[ds];
  float As2 = -expf(Alog[ds * 4 + ss]) * LOG2E;
  float Dd = Dp[ds];
  int kc_d = kpos(ds, 0) & ~28;                       // (ds&~31)+(ds&3)
  int qs_d = sigq((ds >> 2) & 7);

  int sA = r16 & 7;
  int slotA = (g + sA) & 7, slotB = (g + 4 + sA) & 7;

  // prefetch seq 0 H into registers
  uint4 pf0, pf1;
  {
    const uint4* s4 = (const uint4*)(ws + (size_t)blockIdx.x * NSEQ * 8192);
    pf0 = s4[tid * 2];
    pf1 = s4[tid * 2 + 1];
  }

  for (int iseq = 0; iseq < NSEQ; ++iseq) {
    size_t seqoff = ((size_t)blockIdx.x * NSEQ + iseq) * 8192;

    // opaque 0: blocks loop-invariant hoisting of per-seq weight streams
    int opq = 0;
    asm volatile("" : "+v"(opq));

    // ---- P0: commit prefetched packed H to LDS ----
    *(uint4*)&Li[RHP + tid * 8]     = pf0;
    *(uint4*)&Li[RHP + tid * 8 + 4] = pf1;
    __syncthreads();

    // ---- P1: in_proj xz(64x256) = H @ Win^T; wave w -> cols 16w..16w+16 ----
    f32x4 acc[4];
#pragma unroll
    for (int rt = 0; rt < 4; ++rt) acc[rt] = (f32x4){0.f, 0.f, 0.f, 0.f};
#pragma unroll
    for (int kc = 0; kc < 4; ++kc) {
      BU bh, bl;
      bh.q = wih[kc];
      bl.q = wil[kc];
#pragma unroll
      for (int rt = 0; rt < 4; ++rt) {
        int base = RHP + (rt * 16 + r16) * 128 + kc * 32;
        uint4 wa = *(const uint4*)&Li[base + slotA * 4];
        uint4 wb = *(const uint4*)&Li[base + slotB * 4];
        BU ah, al;
        ah.u[0] = __builtin_amdgcn_perm(wa.y, wa.x, SELH);
        ah.u[1] = __builtin_amdgcn_perm(wa.w, wa.z, SELH);
        ah.u[2] = __builtin_amdgcn_perm(wb.y, wb.x, SELH);
        ah.u[3] = __builtin_amdgcn_perm(wb.w, wb.z, SELH);
        al.u[0] = __builtin_amdgcn_perm(wa.y, wa.x, SELL);
        al.u[1] = __builtin_amdgcn_perm(wa.w, wa.z, SELL);
        al.u[2] = __builtin_amdgcn_perm(wb.y, wb.x, SELL);
        al.u[3] = __builtin_amdgcn_perm(wb.w, wb.z, SELL);
        acc[rt] = __builtin_amdgcn_mfma_f32_16x16x32_bf16(al.v, bh.v, acc[rt], 0, 0, 0);
        acc[rt] = __builtin_amdgcn_mfma_f32_16x16x32_bf16(ah.v, bl.v, acc[rt], 0, 0, 0);
        acc[rt] = __builtin_amdgcn_mfma_f32_16x16x32_bf16(ah.v, bh.v, acc[rt], 0, 0, 0);
      }
    }
    __syncthreads();   // H fully consumed; RHP free for next prefetch commit

    // issue next-seq H loads (register-staged; hides under P2..P6)
    if (iseq + 1 < NSEQ) {
      const uint4* s4 = (const uint4*)(ws + seqoff + 8192);
      pf0 = s4[tid * 2];
      pf1 = s4[tid * 2 + 1];
    }

    // ---- P2: scatter: waves 0-7 -> x f32 [t][132]; 8-15 -> silu(z) [d][67] ----
    if (w < 8) {
      int dl0 = w * 16;
#pragma unroll
      for (int rt = 0; rt < 4; ++rt)
#pragma unroll
        for (int r = 0; r < 4; ++r)
          L[R0 + (rt * 16 + g * 4 + r) * 132 + dl0 + r16] = acc[rt][r];
    } else {
      int d = (w - 8) * 16 + r16;
#pragma unroll
      for (int rt = 0; rt < 4; ++rt)
#pragma unroll
        for (int r = 0; r < 4; ++r)
          L[R1 + d * 67 + rt * 16 + g * 4 + r] = fsilu(acc[rt][r]);
    }
    __syncthreads();

    // ---- P3: causal conv(3) + SiLU; packed XC back into R0 (kpos slots) ----
    {
      int t0 = tq * 8;
      float xin[10];
#pragma unroll
      for (int ii = 0; ii < 10; ++ii) {
        int t = t0 - 2 + ii;
        xin[ii] = (t < 0) ? 0.f : L[R0 + t * 132 + dc];
      }
      __syncthreads();   // all pre-conv reads done before overwrite
#pragma unroll
      for (int ii = 0; ii < 8; ++ii) {
        int t = t0 + ii;
        float v = fmaf(cw2, xin[ii + 2], fmaf(cw1, xin[ii + 1], fmaf(cw0, xin[ii], cbv)));
        Li[R0 + t * 132 + kpos(dc, t & 7)] = packsplit(fsilu(v));
      }
    }
    __syncthreads();

    // ---- P4: x_proj x_dbl(64x16) = XC @ Wx^T via MFMA (waves 0-3) ----
    if (w < 4) {
      f32x4 o = (f32x4){0.f, 0.f, 0.f, 0.f};
#pragma unroll
      for (int kc = 0; kc < 4; ++kc) {
        int cb = (r16 * 4 + kc) * 8 + g * 2 + opq;
        BU bh, bl;
        bh.q = wsx4[cb];
        bl.q = wsx4[cb + 1];
        int base = R0 + (w * 16 + r16) * 132 + kc * 32;
        uint4 wa = *(const uint4*)&Li[base + slotA * 4];
        uint4 wb = *(const uint4*)&Li[base + slotB * 4];
        BU ah, al;
        ah.u[0] = __builtin_amdgcn_perm(wa.y, wa.x, SELH);
        ah.u[1] = __builtin_amdgcn_perm(wa.w, wa.z, SELH);
        ah.u[2] = __builtin_amdgcn_perm(wb.y, wb.x, SELH);
        ah.u[3] = __builtin_amdgcn_perm(wb.w, wb.z, SELH);
        al.u[0] = __builtin_amdgcn_perm(wa.y, wa.x, SELL);
        al.u[1] = __builtin_amdgcn_perm(wa.w, wa.z, SELL);
        al.u[2] = __builtin_amdgcn_perm(wb.y, wb.x, SELL);
        al.u[3] = __builtin_amdgcn_perm(wb.w, wb.z, SELL);
        o = __builtin_amdgcn_mfma_f32_16x16x32_bf16(al.v, bh.v, o, 0, 0, 0);
        o = __builtin_amdgcn_mfma_f32_16x16x32_bf16(ah.v, bl.v, o, 0, 0, 0);
        o = __builtin_amdgcn_mfma_f32_16x16x32_bf16(ah.v, bh.v, o, 0, 0, 0);
      }
      // features: dt f (0..7) row-major; B_s -> 8+2s; C_s -> 9+2s
      int p = (r16 < 8) ? r16 : (r16 < 12 ? 8 + 2 * (r16 - 8) : 9 + 2 * (r16 - 12));
#pragma unroll
      for (int q = 0; q < 4; ++q)
        L[RXD + (w * 16 + g * 4 + q) * 20 + p] = o[q];
    }
    __syncthreads();

    // ---- stream out_proj fragments NOW; scan hides the latency ----
    BU p6h[4], p6l[4];
#pragma unroll
    for (int kc = 0; kc < 4; ++kc) {
      int cbo = ((((w & 7) * 16) + r16) * 4 + kc) * 8 + g * 2 + opq;
      p6h[kc].q = wso4[cbo];
      p6l[kc].q = wso4[cbo + 1];
    }

    // ---- P5: selective scan (tid<512): dt-share, packed Y over packed XC ----
    if (tid < 512) {
      float hsv = 0.f;
#pragma unroll 2
      for (int tb = 0; tb < 16; ++tb) {
        int tme = tb * 4 + ss;                        // this lane's dt timestep
        const float* xr = &L[RXD + tme * 20];
        float4 xa = *(const float4*)xr;
        float4 xb = *(const float4*)(xr + 4);
        float dot = bd;
        dot = fmaf(xa.x, wdta.x, dot); dot = fmaf(xa.y, wdta.y, dot);
        dot = fmaf(xa.z, wdta.z, dot); dot = fmaf(xa.w, wdta.w, dot);
        dot = fmaf(xb.x, wdtb.x, dot); dot = fmaf(xb.y, wdtb.y, dot);
        dot = fmaf(xb.z, wdtb.z, dot); dot = fmaf(xb.w, wdtb.w, dot);
        float e = __builtin_amdgcn_exp2f(dot * LOG2E);
        float sp = LN2 * __builtin_amdgcn_logf(1.0f + e);
        float dtme = (dot > 20.f) ? dot : sp;         // softplus(own t)

#define SCANSTEP(SI)                                                          \
        {                                                                     \
          int t = tb * 4 + SI;                                                \
          float dtv = qbcast<SI>(dtme);                                       \
          float2 bc = *(const float2*)&L[RXD + t * 20 + 8 + 2 * ss];          \
          int xoff = R0 + t * 132 + kc_d + (((qs_d + (t & 7)) & 7) << 2);     \
          float xcv = unpacksplit(Li[xoff]);                                  \
          float dA = __builtin_amdgcn_exp2f(dtv * As2);                       \
          hsv = fmaf(hsv, dA, dtv * xcv * bc.x);                              \
          float y = qsum4(hsv * bc.y);                                        \
          if (SI == ss) {                                                     \
            y = fmaf(xcv, Dd, y);                                             \
            y *= L[R1 + ds * 67 + t];                                         \
            Li[xoff] = packsplit(y);                                          \
          }                                                                   \
        }
        SCANSTEP(0)
        SCANSTEP(1)
        SCANSTEP(2)
        SCANSTEP(3)
#undef SCANSTEP
      }
    }
    __syncthreads();

    // ---- P6: out_proj out(64x128) = Y @ Wout^T; wave pair splits rows ----
    {
      int rt0 = (w >> 3) * 2;
      int cc = (w & 7) * 16 + r16;
      f32x4 o[2];
      o[0] = (f32x4){0.f, 0.f, 0.f, 0.f};
      o[1] = (f32x4){0.f, 0.f, 0.f, 0.f};
#pragma unroll
      for (int kc = 0; kc < 4; ++kc) {
#pragma unroll
        for (int rr = 0; rr < 2; ++rr) {
          int base = R0 + ((rt0 + rr) * 16 + r16) * 132 + kc * 32;
          uint4 wa = *(const uint4*)&Li[base + slotA * 4];
          uint4 wb = *(const uint4*)&Li[base + slotB * 4];
          BU ah, al;
          ah.u[0] = __builtin_amdgcn_perm(wa.y, wa.x, SELH);
          ah.u[1] = __builtin_amdgcn_perm(wa.w, wa.z, SELH);
          ah.u[2] = __builtin_amdgcn_perm(wb.y, wb.x, SELH);
          ah.u[3] = __builtin_amdgcn_perm(wb.w, wb.z, SELH);
          al.u[0] = __builtin_amdgcn_perm(wa.y, wa.x, SELL);
          al.u[1] = __builtin_amdgcn_perm(wa.w, wa.z, SELL);
          al.u[2] = __builtin_amdgcn_perm(wb.y, wb.x, SELL);
          al.u[3] = __builtin_amdgcn_perm(wb.w, wb.z, SELL);
          o[rr] = __builtin_amdgcn_mfma_f32_16x16x32_bf16(al.v, p6h[kc].v, o[rr], 0, 0, 0);
          o[rr] = __builtin_amdgcn_mfma_f32_16x16x32_bf16(ah.v, p6l[kc].v, o[rr], 0, 0, 0);
          o[rr] = __builtin_amdgcn_mfma_f32_16x16x32_bf16(ah.v, p6h[kc].v, o[rr], 0, 0, 0);
        }
      }
      float* yout = (float*)(ws + seqoff);
#pragma unroll
      for (int rr = 0; rr < 2; ++rr)
#pragma unroll
        for (int r = 0; r < 4; ++r)
          yout[((rt0 + rr) * 16 + g * 4 + r) * C_ + cc] = o[rr][r];
    }
    __syncthreads();   // LDS reuse next sequence
  }
}

// ---------------- K3: transpose (B*N,T,C) -> (B,C,T,N) ----------------------
__global__ __launch_bounds__(256) void k_out_tr(const float* __restrict__ ws_y,
                                                float* __restrict__ out) {
  __shared__ float tile[32 * 132];
  int bx = blockIdx.x;
  int nt = bx & 7, t = (bx >> 3) & 63, b = bx >> 9;
  int n0 = nt * 32;
  int tid = threadIdx.x;
  const float4* y4 = (const float4*)ws_y;
  for (int it = 0; it < 4; ++it) {
    int idx4 = it * 256 + tid;
    int nn = idx4 >> 5, c4 = idx4 & 31;
    float4 v = y4[((b * N_ + n0 + nn) * (long)T_ + t) * (C_ / 4) + c4];
    *(float4*)&tile[nn * 132 + c4 * 4] = v;
  }
  __syncthreads();
  int nn = tid & 31, cg = tid >> 5;
  for (int i = 0; i < 16; ++i) {
    int c = cg * 16 + i;
    out[((b * C_ + c) * (long)T_ + t) * N_ + n0 + nn] = tile[nn * 132 + c];
  }
}

extern "C" void kernel_launch(void* const* d_in, const int* in_sizes, int n_in,
                              void* d_out, int out_size, void* d_ws, size_t ws_size,
                              hipStream_t stream) {
  const float* x    = (const float*)d_in[0];
  const float* gam  = (const float*)d_in[1];
  const float* bet  = (const float*)d_in[2];
  const float* Win  = (const float*)d_in[3];
  const float* cw   = (const float*)d_in[4];
  const float* cb   = (const float*)d_in[5];
  const float* Wx   = (const float*)d_in[6];
  const float* Wdt  = (const float*)d_in[7];
  const float* bdt  = (const float*)d_in[8];
  const float* Alog = (const float*)d_in[9];
  const float* Dp   = (const float*)d_in[10];
  const float* Wout = (const float*)d_in[11];
  float* out = (float*)d_out;
  unsigned* ws = (unsigned*)d_ws;  // 64 MiB: packed H image -> y f32 in place

  // split-weight storage: ws tail if it fits, else scribble d_out
  const size_t HBYTES = 67108864ull;                      // 64 MiB
  const size_t WBYTES = 131072ull + 65536ull + 8192ull;   // Win + Wout + Wx splits
  char* wtail;
  if (ws_size >= HBYTES + WBYTES) wtail = (char*)d_ws + HBYTES;
  else                            wtail = (char*)d_out;
  ushort_t* wsi = (ushort_t*)wtail;
  ushort_t* wso = (ushort_t*)(wtail + 131072);
  ushort_t* wsx = (ushort_t*)(wtail + 131072 + 65536);

  (void)hipFuncSetAttribute((const void*)k_mamba,
                            hipFuncAttributeMaxDynamicSharedMemorySize,
                            LDSW * 4);

  k_wsplit<<<4, 512, 0, stream>>>(Win, Wout, Wx, wsi, wso, wsx);
  k_ln<<<4096, 256, 0, stream>>>(x, gam, bet, ws);
  k_mamba<<<2048 / NSEQ, 1024, LDSW * 4, stream>>>(ws, wsi, wso, wsx, cw, cb,
                                                   Wdt, bdt, Alog, Dp);
  k_out_tr<<<4096, 256, 0, stream>>>((const float*)ws, out);
}

// Round 12
// 212.402 us; speedup vs baseline: 1.4355x; 1.3272x over previous
//
#include <hip/hip_runtime.h>
#include <math.h>

#define B_   8
#define C_   128
#define T_   64
#define N_   256
#define NSEQ 4

typedef __attribute__((ext_vector_type(8))) short bf16x8;
typedef __attribute__((ext_vector_type(4))) float f32x4;
typedef unsigned short ushort_t;

#define LOG2E 1.4426950408889634f
#define LN2   0.6931471805599453f

// ---- LDS word layout (27008 words = 108032 B, 1 block/CU at 8 waves) ----
#define RH   0       // [64][68] u32: H hi-plane pairs -> Y hi-plane (P5/P6)
#define RL   4352    // [64][68] u32: H lo-plane pairs -> Y lo-plane
#define R0   8704    // [64][132]: x f32 (P2) -> packed XC u32 (P3..P5)
#define R1   17152   // [128][67] f32: silu(z), [d][t]
#define RXD  25728   // [64][20] f32: x_dbl: dt f0..7 row-major; B_s at 8+2s; C_s at 9+2s
#define LDSW 27008

// ---------------- helpers ----------------------------------------------------
__device__ __forceinline__ unsigned bfhi(float x) {  // RNE f32->bf16 (as u32)
  unsigned u = __float_as_uint(x);
  return (u + 0x7FFF + ((u >> 16) & 1)) >> 16;
}
__device__ __forceinline__ unsigned packsplit(float x) {  // (lo<<16)|hi
  unsigned hi = bfhi(x);
  float rem = x - __uint_as_float(hi << 16);
  unsigned lo = bfhi(rem);
  return (hi & 0xFFFFu) | (lo << 16);
}
__device__ __forceinline__ float unpacksplit(unsigned u) {
  return __uint_as_float(u << 16) + __uint_as_float(u & 0xFFFF0000u);
}
__device__ __forceinline__ float fsilu(float v) {
  return v * __builtin_amdgcn_rcpf(1.0f + __builtin_amdgcn_exp2f(-LOG2E * v));
}
__device__ __forceinline__ float qsum4(float v) {  // sum over lane quads (DPP)
  int x = __builtin_amdgcn_update_dpp(0, __float_as_int(v), 0xB1, 0xF, 0xF, true);
  v += __int_as_float(x);
  x = __builtin_amdgcn_update_dpp(0, __float_as_int(v), 0x4E, 0xF, 0xF, true);
  v += __int_as_float(x);
  return v;
}
template <int SI>
__device__ __forceinline__ float qbcast(float v) {  // broadcast quad-lane SI
  constexpr int sel = SI | (SI << 2) | (SI << 4) | (SI << 6);
  return __int_as_float(__builtin_amdgcn_update_dpp(0, __float_as_int(v), sel, 0xF, 0xF, true));
}
// packed-XC k-quad permutation (bank-uniform reads in P4/scan; r9-proven)
__device__ __forceinline__ int sigq(int qk) { return (qk >> 1) | ((qk & 1) << 2); }
__device__ __forceinline__ int kpos(int k, int s) {
  return (k & ~31) + ((((sigq((k >> 2) & 7)) + s) & 7) << 2) + (k & 3);
}
union BU { uint4 q; bf16x8 v; unsigned u[4]; };

// ---------------- K0: pre-split weights into MFMA fragment layout -----------
__global__ __launch_bounds__(512) void k_wsplit(const float* __restrict__ Win,
                                                const float* __restrict__ Wout,
                                                const float* __restrict__ Wx,
                                                ushort_t* __restrict__ wsi,
                                                ushort_t* __restrict__ wso,
                                                ushort_t* __restrict__ wsx) {
  int idx = blockIdx.x * 512 + threadIdx.x;
  const float* src;
  ushort_t* dst;
  if (idx < 1024) {
    int row = idx >> 2, kc = idx & 3;
    src = Win + row * 128 + kc * 32;
    dst = wsi + (row * 4 + kc) * 64;
  } else if (idx < 1536) {
    int k = idx - 1024;
    int row = k >> 2, kc = k & 3;
    src = Wout + row * 128 + kc * 32;
    dst = wso + (row * 4 + kc) * 64;
  } else if (idx < 1600) {
    int k = idx - 1536;
    int row = k >> 2, kc = k & 3;
    src = Wx + row * 128 + kc * 32;
    dst = wsx + (row * 4 + kc) * 64;
  } else {
    return;
  }
  for (int g = 0; g < 4; ++g) {
    unsigned hw[4], lw[4];
#pragma unroll
    for (int e2 = 0; e2 < 4; ++e2) {
      float x0 = src[g * 8 + 2 * e2], x1 = src[g * 8 + 2 * e2 + 1];
      unsigned p0 = packsplit(x0), p1 = packsplit(x1);
      hw[e2] = (p0 & 0xFFFFu) | (p1 << 16);
      lw[e2] = (p0 >> 16) | (p1 & 0xFFFF0000u);
    }
    *(uint4*)(dst + (g * 2 + 0) * 8) = make_uint4(hw[0], hw[1], hw[2], hw[3]);
    *(uint4*)(dst + (g * 2 + 1) * 8) = make_uint4(lw[0], lw[1], lw[2], lw[3]);
  }
}

// ---- K1: LayerNorm + transpose + split-bf16 planes to (B*N)[2][64][64w] ----
__global__ __launch_bounds__(256) void k_ln(const float* __restrict__ x,
                                            const float* __restrict__ gam,
                                            const float* __restrict__ bet,
                                            unsigned* __restrict__ hp) {
  __shared__ float tile[128 * 36];
  __shared__ float ps[8 * 32], pq[8 * 32], mean_s[32], rstd_s[32];
  int bx = blockIdx.x;
  int nt = bx & 7, t = (bx >> 3) & 63, b = bx >> 9;
  int n0 = nt * 32;
  int tid = threadIdx.x;
  const float4* x4 = (const float4*)x;
  for (int it = 0; it < 4; ++it) {
    int idx4 = it * 256 + tid;
    int c = idx4 >> 3, nn4 = idx4 & 7;
    float4 v = x4[((b * C_ + c) * T_ + t) * (N_ / 4) + (n0 >> 2) + nn4];
    *(float4*)&tile[c * 36 + nn4 * 4] = v;
  }
  __syncthreads();
  {
    int nn = tid & 31, cg = tid >> 5;
    float s = 0.f, q = 0.f;
    for (int i = 0; i < 16; ++i) {
      float v = tile[(cg * 16 + i) * 36 + nn];
      s += v; q += v * v;
    }
    ps[cg * 32 + nn] = s; pq[cg * 32 + nn] = q;
  }
  __syncthreads();
  if (tid < 32) {
    float ss = 0.f, qq = 0.f;
    for (int g2 = 0; g2 < 8; ++g2) { ss += ps[g2 * 32 + tid]; qq += pq[g2 * 32 + tid]; }
    float mu = ss * (1.f / 128.f);
    float var = qq * (1.f / 128.f) - mu * mu;
    mean_s[tid] = mu;
    rstd_s[tid] = rsqrtf(var + 1e-5f);
  }
  __syncthreads();
  {
    int c = tid & 127, half = tid >> 7;
    float gm = gam[c], bb = bet[c];
    ushort_t* hp16 = (ushort_t*)hp;
    for (int it = 0; it < 16; ++it) {
      int n = it * 2 + half;
      float v = (tile[c * 36 + n] - mean_s[n]) * rstd_s[n] * gm + bb;
      unsigned h = bfhi(v);
      unsigned l = bfhi(v - __uint_as_float(h << 16));
      size_t sb = (size_t)(b * N_ + n0 + n) * 8192 + t * 64;
      hp16[(sb + (c >> 1)) * 2 + (c & 1)] = (ushort_t)h;          // hi plane
      hp16[(sb + 4096 + (c >> 1)) * 2 + (c & 1)] = (ushort_t)l;   // lo plane
    }
  }
}

// ---------------- K2: fused Mamba (r9 structure, perm-free GEMMs) -----------
// (512,2): the only bounds where the allocator gives a clean ~124-reg
// allocation (r4/r9); min_waves=4 or 1024-thread blocks clamp to 64 + spill.
__global__ __launch_bounds__(512, 2) void k_mamba(
    unsigned* ws,                       // (B*N)[2][64][64w] split H -> y f32
    const ushort_t* __restrict__ wsi,   // pre-split Win fragments
    const ushort_t* __restrict__ wso,   // pre-split Wout fragments
    const ushort_t* __restrict__ wsx,   // pre-split Wx fragments
    const float* __restrict__ convw,    // (3,1,128)
    const float* __restrict__ convb,    // (128)
    const float* __restrict__ Wdt,      // (128,8)
    const float* __restrict__ bdt,      // (128)
    const float* __restrict__ Alog,     // (128,4)
    const float* __restrict__ Dp)       // (128)
{
  extern __shared__ float L[];
  unsigned* Li = (unsigned*)L;
  ushort_t* Ls = (ushort_t*)L;
  int tid = threadIdx.x;
  int lane = tid & 63;
  int w = tid >> 6;                 // wave 0..7
  int r16 = lane & 15, g = lane >> 4;
  const uint4* wsi4 = (const uint4*)wsi;
  const uint4* wso4 = (const uint4*)wso;
  const uint4* wsx4 = (const uint4*)wsx;

  // ---- persistent weight fragments (96 regs, r9-proven allocatable) ----
  uint4 wih[2][4], wil[2][4], woh[4], wol[4];
#pragma unroll
  for (int ci = 0; ci < 2; ++ci)
#pragma unroll
    for (int kc = 0; kc < 4; ++kc) {
      int cb = ((w * 32 + ci * 16 + r16) * 4 + kc) * 8 + g * 2;
      wih[ci][kc] = wsi4[cb];
      wil[ci][kc] = wsi4[cb + 1];
    }
#pragma unroll
  for (int kc = 0; kc < 4; ++kc) {
    int cb = ((w * 16 + r16) * 4 + kc) * 8 + g * 2;
    woh[kc] = wso4[cb];
    wol[kc] = wso4[cb + 1];
  }
  // ---- per-thread constants ----
  int dc = tid & 127, tq = tid >> 7;                  // conv role
  float cw0 = convw[dc], cw1 = convw[128 + dc], cw2 = convw[256 + dc];
  float cbv = convb[dc];
  int ds = tid >> 2, ss = tid & 3;                    // scan role
  float4 wdta = *(const float4*)&Wdt[ds * 8];
  float4 wdtb = *(const float4*)&Wdt[ds * 8 + 4];
  float bd = bdt[ds];
  float As2 = -expf(Alog[ds * 4 + ss]) * LOG2E;
  float Dd = Dp[ds];
  int kc_d = (ds & ~31) + (ds & 3);                   // packed-XC addr pieces
  int qs_d = sigq((ds >> 2) & 7);

  for (int iseq = 0; iseq < NSEQ; ++iseq) {
    size_t seqoff = ((size_t)blockIdx.x * NSEQ + iseq) * 8192;

    // ---- P0: copy split H planes into RH/RL (pure b128 copy) ----
    {
      const uint4* s4 = (const uint4*)(ws + seqoff);
#pragma unroll
      for (int q = 0; q < 4; ++q) {
        int j = q * 512 + tid;            // uint4 index in [0,2048)
        int plane = j >> 10, jj = j & 1023;
        int row = jj >> 4, c4 = jj & 15;
        uint4 v = s4[j];
        *(uint4*)&Li[(plane ? RL : RH) + row * 68 + c4 * 4] = v;
      }
    }
    __syncthreads();

    // ---- P1: in_proj xz(64x256) = H @ Win^T (direct b128 fragments) ----
    f32x4 acc[4][2];
#pragma unroll
    for (int rt = 0; rt < 4; ++rt)
#pragma unroll
      for (int ci = 0; ci < 2; ++ci) acc[rt][ci] = (f32x4){0.f, 0.f, 0.f, 0.f};
#pragma unroll
    for (int kc = 0; kc < 4; ++kc) {
      BU bh0, bl0, bh1, bl1;
      bh0.q = wih[0][kc]; bl0.q = wil[0][kc];
      bh1.q = wih[1][kc]; bl1.q = wil[1][kc];
#pragma unroll
      for (int rt = 0; rt < 4; ++rt) {
        int base = (rt * 16 + r16) * 68 + kc * 16 + g * 4;
        BU ah, al;
        ah.q = *(const uint4*)&Li[RH + base];
        al.q = *(const uint4*)&Li[RL + base];
        acc[rt][0] = __builtin_amdgcn_mfma_f32_16x16x32_bf16(al.v, bh0.v, acc[rt][0], 0, 0, 0);
        acc[rt][0] = __builtin_amdgcn_mfma_f32_16x16x32_bf16(ah.v, bl0.v, acc[rt][0], 0, 0, 0);
        acc[rt][0] = __builtin_amdgcn_mfma_f32_16x16x32_bf16(ah.v, bh0.v, acc[rt][0], 0, 0, 0);
        acc[rt][1] = __builtin_amdgcn_mfma_f32_16x16x32_bf16(al.v, bh1.v, acc[rt][1], 0, 0, 0);
        acc[rt][1] = __builtin_amdgcn_mfma_f32_16x16x32_bf16(ah.v, bl1.v, acc[rt][1], 0, 0, 0);
        acc[rt][1] = __builtin_amdgcn_mfma_f32_16x16x32_bf16(ah.v, bh1.v, acc[rt][1], 0, 0, 0);
      }
    }
    // (no barrier: P2 writes R0/R1, disjoint from RH/RL; Y writes come after
    //  the P4 barrier, long past every wave's P1 reads)

    // ---- P2: scatter: waves 0-3 -> x f32 [t][132] (R0); 4-7 -> silu(z) (R1) ----
    {
      int dl0 = (w & 3) * 32;
      if (w < 4) {
#pragma unroll
        for (int rt = 0; rt < 4; ++rt)
#pragma unroll
          for (int ci = 0; ci < 2; ++ci)
#pragma unroll
            for (int r = 0; r < 4; ++r)
              L[R0 + (rt * 16 + g * 4 + r) * 132 + dl0 + ci * 16 + r16] = acc[rt][ci][r];
      } else {
#pragma unroll
        for (int rt = 0; rt < 4; ++rt)
#pragma unroll
          for (int ci = 0; ci < 2; ++ci)
#pragma unroll
            for (int r = 0; r < 4; ++r)
              L[R1 + (dl0 + ci * 16 + r16) * 67 + rt * 16 + g * 4 + r] = fsilu(acc[rt][ci][r]);
      }
    }
    __syncthreads();

    // ---- P3: causal conv(3) + SiLU; packed XC into R0 (sigma slots) ----
    {
      int t0 = tq * 16;
      float xin[18];
#pragma unroll
      for (int ii = 0; ii < 18; ++ii) {
        int t = t0 - 2 + ii;
        xin[ii] = (t < 0) ? 0.f : L[R0 + t * 132 + dc];
      }
      __syncthreads();   // all pre-conv reads done before overwrite
#pragma unroll
      for (int ii = 0; ii < 16; ++ii) {
        int t = t0 + ii;
        float v = fmaf(cw2, xin[ii + 2], fmaf(cw1, xin[ii + 1], fmaf(cw0, xin[ii], cbv)));
        Li[R0 + t * 132 + kpos(dc, t & 7)] = packsplit(fsilu(v));
      }
    }
    __syncthreads();

    // ---- P4: x_proj x_dbl(64x16) = XC @ Wx^T via MFMA (waves 0-3) ----
    if (w < 4) {
      int s = r16 & 7;
      int slotA = (g + s) & 7, slotB = (g + 4 + s) & 7;
      f32x4 o = (f32x4){0.f, 0.f, 0.f, 0.f};
#pragma unroll
      for (int kc = 0; kc < 4; ++kc) {
        int cb = (r16 * 4 + kc) * 8 + g * 2;
        BU bh, bl;
        bh.q = wsx4[cb];
        bl.q = wsx4[cb + 1];
        int base = R0 + (w * 16 + r16) * 132 + kc * 32;
        uint4 wa = *(const uint4*)&Li[base + slotA * 4];
        uint4 wb = *(const uint4*)&Li[base + slotB * 4];
        BU ah, al;
        ah.u[0] = __builtin_amdgcn_perm(wa.y, wa.x, 0x05040100u);
        ah.u[1] = __builtin_amdgcn_perm(wa.w, wa.z, 0x05040100u);
        ah.u[2] = __builtin_amdgcn_perm(wb.y, wb.x, 0x05040100u);
        ah.u[3] = __builtin_amdgcn_perm(wb.w, wb.z, 0x05040100u);
        al.u[0] = __builtin_amdgcn_perm(wa.y, wa.x, 0x07060302u);
        al.u[1] = __builtin_amdgcn_perm(wa.w, wa.z, 0x07060302u);
        al.u[2] = __builtin_amdgcn_perm(wb.y, wb.x, 0x07060302u);
        al.u[3] = __builtin_amdgcn_perm(wb.w, wb.z, 0x07060302u);
        o = __builtin_amdgcn_mfma_f32_16x16x32_bf16(al.v, bh.v, o, 0, 0, 0);
        o = __builtin_amdgcn_mfma_f32_16x16x32_bf16(ah.v, bl.v, o, 0, 0, 0);
        o = __builtin_amdgcn_mfma_f32_16x16x32_bf16(ah.v, bh.v, o, 0, 0, 0);
      }
      // dt feats f0..7 row-major; B_s -> 8+2s; C_s -> 9+2s
      int p = (r16 < 8) ? r16 : (r16 < 12 ? 8 + 2 * (r16 - 8) : 9 + 2 * (r16 - 12));
#pragma unroll
      for (int q = 0; q < 4; ++q)
        L[RXD + (w * 16 + g * 4 + q) * 20 + p] = o[q];
    }
    __syncthreads();

    // ---- P5: scan, dt-share; Y written SPLIT (b16 x2) into RH/RL ----
    {
      float hsv = 0.f;
#pragma unroll 4
      for (int tb = 0; tb < 16; ++tb) {
        int tme = tb * 4 + ss;                        // this lane's dt timestep
        const float* xr = &L[RXD + tme * 20];
        float4 xa = *(const float4*)xr;
        float4 xb = *(const float4*)(xr + 4);
        float dot = bd;
        dot = fmaf(xa.x, wdta.x, dot); dot = fmaf(xa.y, wdta.y, dot);
        dot = fmaf(xa.z, wdta.z, dot); dot = fmaf(xa.w, wdta.w, dot);
        dot = fmaf(xb.x, wdtb.x, dot); dot = fmaf(xb.y, wdtb.y, dot);
        dot = fmaf(xb.z, wdtb.z, dot); dot = fmaf(xb.w, wdtb.w, dot);
        float e = __builtin_amdgcn_exp2f(dot * LOG2E);
        float sp = LN2 * __builtin_amdgcn_logf(1.0f + e);
        float dtme = (dot > 20.f) ? dot : sp;         // softplus(own t)

#define SCANSTEP(SI)                                                          \
        {                                                                     \
          int t = tb * 4 + SI;                                                \
          float dtv = qbcast<SI>(dtme);                                       \
          float2 bc = *(const float2*)&L[RXD + t * 20 + 8 + 2 * ss];          \
          int xoff = R0 + t * 132 + kc_d + (((qs_d + (t & 7)) & 7) << 2);     \
          float xcv = unpacksplit(Li[xoff]);                                  \
          float dA = __builtin_amdgcn_exp2f(dtv * As2);                       \
          hsv = fmaf(hsv, dA, dtv * xcv * bc.x);                              \
          float y = qsum4(hsv * bc.y);                                        \
          if (SI == ss) {                                                     \
            y = fmaf(xcv, Dd, y);                                             \
            y *= L[R1 + ds * 67 + t];                                         \
            unsigned yh = bfhi(y);                                            \
            unsigned yl = bfhi(y - __uint_as_float(yh << 16));                \
            int wi = t * 68 + (ds >> 1);                                      \
            Ls[(RH + wi) * 2 + (ds & 1)] = (ushort_t)yh;                      \
            Ls[(RL + wi) * 2 + (ds & 1)] = (ushort_t)yl;                      \
          }                                                                   \
        }
        SCANSTEP(0)
        SCANSTEP(1)
        SCANSTEP(2)
        SCANSTEP(3)
#undef SCANSTEP
      }
    }
    __syncthreads();

    // ---- P6: out_proj out(64x128) = Y @ Wout^T (direct b128 fragments) ----
    {
      f32x4 o[4];
#pragma unroll
      for (int rt = 0; rt < 4; ++rt) o[rt] = (f32x4){0.f, 0.f, 0.f, 0.f};
#pragma unroll
      for (int kc = 0; kc < 4; ++kc) {
        BU bh, bl;
        bh.q = woh[kc];
        bl.q = wol[kc];
#pragma unroll
        for (int rt = 0; rt < 4; ++rt) {
          int base = (rt * 16 + r16) * 68 + kc * 16 + g * 4;
          BU ah, al;
          ah.q = *(const uint4*)&Li[RH + base];
          al.q = *(const uint4*)&Li[RL + base];
          o[rt] = __builtin_amdgcn_mfma_f32_16x16x32_bf16(al.v, bh.v, o[rt], 0, 0, 0);
          o[rt] = __builtin_amdgcn_mfma_f32_16x16x32_bf16(ah.v, bl.v, o[rt], 0, 0, 0);
          o[rt] = __builtin_amdgcn_mfma_f32_16x16x32_bf16(ah.v, bh.v, o[rt], 0, 0, 0);
        }
      }
      float* yout = (float*)(ws + seqoff);   // y f32 overwrites this seq's H
#pragma unroll
      for (int rt = 0; rt < 4; ++rt)
#pragma unroll
        for (int r = 0; r < 4; ++r)
          yout[(rt * 16 + g * 4 + r) * C_ + w * 16 + r16] = o[rt][r];
    }
    __syncthreads();   // RH/RL reuse next sequence
  }
}

// ---------------- K3: transpose (B*N,T,C) -> (B,C,T,N) ----------------------
__global__ __launch_bounds__(256) void k_out_tr(const float* __restrict__ ws_y,
                                                float* __restrict__ out) {
  __shared__ float tile[32 * 132];
  int bx = blockIdx.x;
  int nt = bx & 7, t = (bx >> 3) & 63, b = bx >> 9;
  int n0 = nt * 32;
  int tid = threadIdx.x;
  const float4* y4 = (const float4*)ws_y;
  for (int it = 0; it < 4; ++it) {
    int idx4 = it * 256 + tid;
    int nn = idx4 >> 5, c4 = idx4 & 31;
    float4 v = y4[((b * N_ + n0 + nn) * (long)T_ + t) * (C_ / 4) + c4];
    *(float4*)&tile[nn * 132 + c4 * 4] = v;
  }
  __syncthreads();
  int nn = tid & 31, cg = tid >> 5;
  for (int i = 0; i < 16; ++i) {
    int c = cg * 16 + i;
    out[((b * C_ + c) * (long)T_ + t) * N_ + n0 + nn] = tile[nn * 132 + c];
  }
}

extern "C" void kernel_launch(void* const* d_in, const int* in_sizes, int n_in,
                              void* d_out, int out_size, void* d_ws, size_t ws_size,
                              hipStream_t stream) {
  const float* x    = (const float*)d_in[0];
  const float* gam  = (const float*)d_in[1];
  const float* bet  = (const float*)d_in[2];
  const float* Win  = (const float*)d_in[3];
  const float* cw   = (const float*)d_in[4];
  const float* cb   = (const float*)d_in[5];
  const float* Wx   = (const float*)d_in[6];
  const float* Wdt  = (const float*)d_in[7];
  const float* bdt  = (const float*)d_in[8];
  const float* Alog = (const float*)d_in[9];
  const float* Dp   = (const float*)d_in[10];
  const float* Wout = (const float*)d_in[11];
  float* out = (float*)d_out;
  unsigned* ws = (unsigned*)d_ws;  // 64 MiB: split-H planes -> y f32 in place

  // split-weight storage: ws tail if it fits, else scribble d_out
  const size_t HBYTES = 67108864ull;                      // 64 MiB
  const size_t WBYTES = 131072ull + 65536ull + 8192ull;   // Win + Wout + Wx splits
  char* wtail;
  if (ws_size >= HBYTES + WBYTES) wtail = (char*)d_ws + HBYTES;
  else                            wtail = (char*)d_out;
  ushort_t* wsi = (ushort_t*)wtail;
  ushort_t* wso = (ushort_t*)(wtail + 131072);
  ushort_t* wsx = (ushort_t*)(wtail + 131072 + 65536);

  (void)hipFuncSetAttribute((const void*)k_mamba,
                            hipFuncAttributeMaxDynamicSharedMemorySize,
                            LDSW * 4);

  k_wsplit<<<4, 512, 0, stream>>>(Win, Wout, Wx, wsi, wso, wsx);
  k_ln<<<4096, 256, 0, stream>>>(x, gam, bet, ws);
  k_mamba<<<2048 / NSEQ, 512, LDSW * 4, stream>>>(ws, wsi, wso, wsx, cw, cb,
                                                  Wdt, bdt, Alog, Dp);
  k_out_tr<<<4096, 256, 0, stream>>>((const float*)ws, out);
}

// Round 13
// 195.055 us; speedup vs baseline: 1.5632x; 1.0889x over previous
//
#include <hip/hip_runtime.h>
#include <math.h>

#define B_   8
#define C_   128
#define T_   64
#define N_   256
#define NSEQ 8

typedef __attribute__((ext_vector_type(8))) short bf16x8;
typedef __attribute__((ext_vector_type(4))) float f32x4;
typedef unsigned short ushort_t;

#define LOG2E 1.4426950408889634f
#define LN2   0.6931471805599453f

// ---- LDS word layout (35456 words = 141824 B, 1 block/CU at 8 waves) ----
#define RH   0       // [64][68] u32: H hi-plane pairs -> Y hi-plane (P5/P6)
#define RL   4352    // [64][68] u32: H lo-plane pairs -> Y lo-plane
#define R0   8704    // [64][132] f32: x (post in_proj), consumed by conv
#define R1   17152   // [128][67] f32: silu(z), [d][t]
#define RXD  25728   // [64][20] f32: x_dbl: dt f0..7 row-major; B_s at 8+2s; C_s at 9+2s
#define RXC  27008   // [64][132] u32: packed XC (sigma slots), read by P4/P5
#define LDSW 35456

// ---------------- helpers ----------------------------------------------------
__device__ __forceinline__ unsigned bfhi(float x) {  // RNE f32->bf16 (as u32)
  unsigned u = __float_as_uint(x);
  return (u + 0x7FFF + ((u >> 16) & 1)) >> 16;
}
__device__ __forceinline__ unsigned packsplit(float x) {  // (lo<<16)|hi
  unsigned hi = bfhi(x);
  float rem = x - __uint_as_float(hi << 16);
  unsigned lo = bfhi(rem);
  return (hi & 0xFFFFu) | (lo << 16);
}
__device__ __forceinline__ float unpacksplit(unsigned u) {
  return __uint_as_float(u << 16) + __uint_as_float(u & 0xFFFF0000u);
}
__device__ __forceinline__ float fsilu(float v) {
  return v * __builtin_amdgcn_rcpf(1.0f + __builtin_amdgcn_exp2f(-LOG2E * v));
}
__device__ __forceinline__ float qsum4(float v) {  // sum over lane quads (DPP)
  int x = __builtin_amdgcn_update_dpp(0, __float_as_int(v), 0xB1, 0xF, 0xF, true);
  v += __int_as_float(x);
  x = __builtin_amdgcn_update_dpp(0, __float_as_int(v), 0x4E, 0xF, 0xF, true);
  v += __int_as_float(x);
  return v;
}
template <int SI>
__device__ __forceinline__ float qbcast(float v) {  // broadcast quad-lane SI
  constexpr int sel = SI | (SI << 2) | (SI << 4) | (SI << 6);
  return __int_as_float(__builtin_amdgcn_update_dpp(0, __float_as_int(v), sel, 0xF, 0xF, true));
}
// packed-XC k-quad permutation (bank-uniform reads in P4/scan)
__device__ __forceinline__ int sigq(int qk) { return (qk >> 1) | ((qk & 1) << 2); }
__device__ __forceinline__ int kpos(int k, int s) {
  return (k & ~31) + ((((sigq((k >> 2) & 7)) + s) & 7) << 2) + (k & 3);
}
union BU { uint4 q; bf16x8 v; unsigned u[4]; };

// ---------------- K0: pre-split weights into MFMA fragment layout -----------
__global__ __launch_bounds__(512) void k_wsplit(const float* __restrict__ Win,
                                                const float* __restrict__ Wout,
                                                const float* __restrict__ Wx,
                                                ushort_t* __restrict__ wsi,
                                                ushort_t* __restrict__ wso,
                                                ushort_t* __restrict__ wsx) {
  int idx = blockIdx.x * 512 + threadIdx.x;
  const float* src;
  ushort_t* dst;
  if (idx < 1024) {
    int row = idx >> 2, kc = idx & 3;
    src = Win + row * 128 + kc * 32;
    dst = wsi + (row * 4 + kc) * 64;
  } else if (idx < 1536) {
    int k = idx - 1024;
    int row = k >> 2, kc = k & 3;
    src = Wout + row * 128 + kc * 32;
    dst = wso + (row * 4 + kc) * 64;
  } else if (idx < 1600) {
    int k = idx - 1536;
    int row = k >> 2, kc = k & 3;
    src = Wx + row * 128 + kc * 32;
    dst = wsx + (row * 4 + kc) * 64;
  } else {
    return;
  }
  for (int g = 0; g < 4; ++g) {
    unsigned hw[4], lw[4];
#pragma unroll
    for (int e2 = 0; e2 < 4; ++e2) {
      float x0 = src[g * 8 + 2 * e2], x1 = src[g * 8 + 2 * e2 + 1];
      unsigned p0 = packsplit(x0), p1 = packsplit(x1);
      hw[e2] = (p0 & 0xFFFFu) | (p1 << 16);
      lw[e2] = (p0 >> 16) | (p1 & 0xFFFF0000u);
    }
    *(uint4*)(dst + (g * 2 + 0) * 8) = make_uint4(hw[0], hw[1], hw[2], hw[3]);
    *(uint4*)(dst + (g * 2 + 1) * 8) = make_uint4(lw[0], lw[1], lw[2], lw[3]);
  }
}

// ---- K1: LayerNorm + transpose + split-bf16 planes to (B*N)[2][64][64w] ----
__global__ __launch_bounds__(256) void k_ln(const float* __restrict__ x,
                                            const float* __restrict__ gam,
                                            const float* __restrict__ bet,
                                            unsigned* __restrict__ hp) {
  __shared__ float tile[128 * 36];
  __shared__ float ps[8 * 32], pq[8 * 32], mean_s[32], rstd_s[32];
  int bx = blockIdx.x;
  int nt = bx & 7, t = (bx >> 3) & 63, b = bx >> 9;
  int n0 = nt * 32;
  int tid = threadIdx.x;
  const float4* x4 = (const float4*)x;
  for (int it = 0; it < 4; ++it) {
    int idx4 = it * 256 + tid;
    int c = idx4 >> 3, nn4 = idx4 & 7;
    float4 v = x4[((b * C_ + c) * T_ + t) * (N_ / 4) + (n0 >> 2) + nn4];
    *(float4*)&tile[c * 36 + nn4 * 4] = v;
  }
  __syncthreads();
  {
    int nn = tid & 31, cg = tid >> 5;
    float s = 0.f, q = 0.f;
    for (int i = 0; i < 16; ++i) {
      float v = tile[(cg * 16 + i) * 36 + nn];
      s += v; q += v * v;
    }
    ps[cg * 32 + nn] = s; pq[cg * 32 + nn] = q;
  }
  __syncthreads();
  if (tid < 32) {
    float ss = 0.f, qq = 0.f;
    for (int g2 = 0; g2 < 8; ++g2) { ss += ps[g2 * 32 + tid]; qq += pq[g2 * 32 + tid]; }
    float mu = ss * (1.f / 128.f);
    float var = qq * (1.f / 128.f) - mu * mu;
    mean_s[tid] = mu;
    rstd_s[tid] = rsqrtf(var + 1e-5f);
  }
  __syncthreads();
  {
    int c = tid & 127, half = tid >> 7;
    float gm = gam[c], bb = bet[c];
    ushort_t* hp16 = (ushort_t*)hp;
    for (int it = 0; it < 16; ++it) {
      int n = it * 2 + half;
      float v = (tile[c * 36 + n] - mean_s[n]) * rstd_s[n] * gm + bb;
      unsigned h = bfhi(v);
      unsigned l = bfhi(v - __uint_as_float(h << 16));
      size_t sb = (size_t)(b * N_ + n0 + n) * 8192 + t * 64;
      hp16[(sb + (c >> 1)) * 2 + (c & 1)] = (ushort_t)h;          // hi plane
      hp16[(sb + 4096 + (c >> 1)) * 2 + (c & 1)] = (ushort_t)l;   // lo plane
    }
  }
}

// ---------------- K2: fused Mamba (r12 + prefetch + RXC + scan batching) ----
// (512,2): clean allocation tier. Total regs (VGPR+acc) land in the 129-256
// band -> 2 waves/SIMD regardless; ~100 regs of FREE headroom exploited here
// for H prefetch and scan load batching.
__global__ __launch_bounds__(512, 2) void k_mamba(
    unsigned* ws,                       // (B*N)[2][64][64w] split H -> y f32
    const ushort_t* __restrict__ wsi,   // pre-split Win fragments
    const ushort_t* __restrict__ wso,   // pre-split Wout fragments
    const ushort_t* __restrict__ wsx,   // pre-split Wx fragments
    const float* __restrict__ convw,    // (3,1,128)
    const float* __restrict__ convb,    // (128)
    const float* __restrict__ Wdt,     // (128,8)
    const float* __restrict__ bdt,      // (128)
    const float* __restrict__ Alog,     // (128,4)
    const float* __restrict__ Dp)       // (128)
{
  extern __shared__ float L[];
  unsigned* Li = (unsigned*)L;
  ushort_t* Ls = (ushort_t*)L;
  int tid = threadIdx.x;
  int lane = tid & 63;
  int w = tid >> 6;                 // wave 0..7
  int r16 = lane & 15, g = lane >> 4;
  const uint4* wsi4 = (const uint4*)wsi;
  const uint4* wso4 = (const uint4*)wso;
  const uint4* wsx4 = (const uint4*)wsx;

  // ---- persistent weight fragments (96 regs) ----
  uint4 wih[2][4], wil[2][4], woh[4], wol[4];
#pragma unroll
  for (int ci = 0; ci < 2; ++ci)
#pragma unroll
    for (int kc = 0; kc < 4; ++kc) {
      int cb = ((w * 32 + ci * 16 + r16) * 4 + kc) * 8 + g * 2;
      wih[ci][kc] = wsi4[cb];
      wil[ci][kc] = wsi4[cb + 1];
    }
#pragma unroll
  for (int kc = 0; kc < 4; ++kc) {
    int cb = ((w * 16 + r16) * 4 + kc) * 8 + g * 2;
    woh[kc] = wso4[cb];
    wol[kc] = wso4[cb + 1];
  }
  // ---- per-thread constants ----
  int dc = tid & 127, tq = tid >> 7;                  // conv role
  float cw0 = convw[dc], cw1 = convw[128 + dc], cw2 = convw[256 + dc];
  float cbv = convb[dc];
  int ds = tid >> 2, ss = tid & 3;                    // scan role
  float4 wdta = *(const float4*)&Wdt[ds * 8];
  float4 wdtb = *(const float4*)&Wdt[ds * 8 + 4];
  float bd = bdt[ds];
  float As2 = -expf(Alog[ds * 4 + ss]) * LOG2E;
  float Dd = Dp[ds];
  int kc_d = (ds & ~31) + (ds & 3);                   // packed-XC addr pieces
  int qs_d = sigq((ds >> 2) & 7);

  // prologue: prefetch seq 0 H
  uint4 pf[4];
  {
    const uint4* s4 = (const uint4*)(ws + (size_t)blockIdx.x * NSEQ * 8192);
#pragma unroll
    for (int q = 0; q < 4; ++q) pf[q] = s4[q * 512 + tid];
  }

  for (int iseq = 0; iseq < NSEQ; ++iseq) {
    size_t seqoff = ((size_t)blockIdx.x * NSEQ + iseq) * 8192;

    // ---- P0: commit prefetched split H planes into RH/RL ----
#pragma unroll
    for (int q = 0; q < 4; ++q) {
      int j = q * 512 + tid;            // uint4 index in [0,2048)
      int plane = j >> 10, jj = j & 1023;
      int row = jj >> 4, c4 = jj & 15;
      *(uint4*)&Li[(plane ? RL : RH) + row * 68 + c4 * 4] = pf[q];
    }
    __syncthreads();

    // ---- P1: in_proj xz(64x256) = H @ Win^T (direct b128 fragments) ----
    f32x4 acc[4][2];
#pragma unroll
    for (int rt = 0; rt < 4; ++rt)
#pragma unroll
      for (int ci = 0; ci < 2; ++ci) acc[rt][ci] = (f32x4){0.f, 0.f, 0.f, 0.f};
#pragma unroll
    for (int kc = 0; kc < 4; ++kc) {
      BU bh0, bl0, bh1, bl1;
      bh0.q = wih[0][kc]; bl0.q = wil[0][kc];
      bh1.q = wih[1][kc]; bl1.q = wil[1][kc];
#pragma unroll
      for (int rt = 0; rt < 4; ++rt) {
        int base = (rt * 16 + r16) * 68 + kc * 16 + g * 4;
        BU ah, al;
        ah.q = *(const uint4*)&Li[RH + base];
        al.q = *(const uint4*)&Li[RL + base];
        acc[rt][0] = __builtin_amdgcn_mfma_f32_16x16x32_bf16(al.v, bh0.v, acc[rt][0], 0, 0, 0);
        acc[rt][0] = __builtin_amdgcn_mfma_f32_16x16x32_bf16(ah.v, bl0.v, acc[rt][0], 0, 0, 0);
        acc[rt][0] = __builtin_amdgcn_mfma_f32_16x16x32_bf16(ah.v, bh0.v, acc[rt][0], 0, 0, 0);
        acc[rt][1] = __builtin_amdgcn_mfma_f32_16x16x32_bf16(al.v, bh1.v, acc[rt][1], 0, 0, 0);
        acc[rt][1] = __builtin_amdgcn_mfma_f32_16x16x32_bf16(ah.v, bl1.v, acc[rt][1], 0, 0, 0);
        acc[rt][1] = __builtin_amdgcn_mfma_f32_16x16x32_bf16(ah.v, bh1.v, acc[rt][1], 0, 0, 0);
      }
    }
    // issue next-seq H prefetch now (H consumed); commits at next loop top.
    // Latency hides under P2..P6 (several barriers + the long scan).
    if (iseq + 1 < NSEQ) {
      const uint4* s4n = (const uint4*)(ws + seqoff + 8192);
#pragma unroll
      for (int q = 0; q < 4; ++q) pf[q] = s4n[q * 512 + tid];
    }
    // (no barrier: P2 writes R0/R1, disjoint from RH/RL; Y writes into RH/RL
    //  happen in P5, separated from P1 reads by the P2/P3/P4 barriers)

    // ---- P2: scatter: waves 0-3 -> x f32 [t][132] (R0); 4-7 -> silu(z) (R1) ----
    {
      int dl0 = (w & 3) * 32;
      if (w < 4) {
#pragma unroll
        for (int rt = 0; rt < 4; ++rt)
#pragma unroll
          for (int ci = 0; ci < 2; ++ci)
#pragma unroll
            for (int r = 0; r < 4; ++r)
              L[R0 + (rt * 16 + g * 4 + r) * 132 + dl0 + ci * 16 + r16] = acc[rt][ci][r];
      } else {
#pragma unroll
        for (int rt = 0; rt < 4; ++rt)
#pragma unroll
          for (int ci = 0; ci < 2; ++ci)
#pragma unroll
            for (int r = 0; r < 4; ++r)
              L[R1 + (dl0 + ci * 16 + r16) * 67 + rt * 16 + g * 4 + r] = fsilu(acc[rt][ci][r]);
      }
    }
    __syncthreads();

    // ---- P3: causal conv(3) + SiLU; read R0, write packed XC -> RXC ----
    // (separate region: no read-before-overwrite mid-barrier needed)
    {
      int t0 = tq * 16;
      float xin[18];
#pragma unroll
      for (int ii = 0; ii < 18; ++ii) {
        int t = t0 - 2 + ii;
        xin[ii] = (t < 0) ? 0.f : L[R0 + t * 132 + dc];
      }
#pragma unroll
      for (int ii = 0; ii < 16; ++ii) {
        int t = t0 + ii;
        float v = fmaf(cw2, xin[ii + 2], fmaf(cw1, xin[ii + 1], fmaf(cw0, xin[ii], cbv)));
        Li[RXC + t * 132 + kpos(dc, t & 7)] = packsplit(fsilu(v));
      }
    }
    __syncthreads();

    // ---- P4: x_proj x_dbl(64x16) = XC @ Wx^T via MFMA (waves 0-3) ----
    if (w < 4) {
      int s = r16 & 7;
      int slotA = (g + s) & 7, slotB = (g + 4 + s) & 7;
      f32x4 o = (f32x4){0.f, 0.f, 0.f, 0.f};
#pragma unroll
      for (int kc = 0; kc < 4; ++kc) {
        int cb = (r16 * 4 + kc) * 8 + g * 2;
        BU bh, bl;
        bh.q = wsx4[cb];
        bl.q = wsx4[cb + 1];
        int base = RXC + (w * 16 + r16) * 132 + kc * 32;
        uint4 wa = *(const uint4*)&Li[base + slotA * 4];
        uint4 wb = *(const uint4*)&Li[base + slotB * 4];
        BU ah, al;
        ah.u[0] = __builtin_amdgcn_perm(wa.y, wa.x, 0x05040100u);
        ah.u[1] = __builtin_amdgcn_perm(wa.w, wa.z, 0x05040100u);
        ah.u[2] = __builtin_amdgcn_perm(wb.y, wb.x, 0x05040100u);
        ah.u[3] = __builtin_amdgcn_perm(wb.w, wb.z, 0x05040100u);
        al.u[0] = __builtin_amdgcn_perm(wa.y, wa.x, 0x07060302u);
        al.u[1] = __builtin_amdgcn_perm(wa.w, wa.z, 0x07060302u);
        al.u[2] = __builtin_amdgcn_perm(wb.y, wb.x, 0x07060302u);
        al.u[3] = __builtin_amdgcn_perm(wb.w, wb.z, 0x07060302u);
        o = __builtin_amdgcn_mfma_f32_16x16x32_bf16(al.v, bh.v, o, 0, 0, 0);
        o = __builtin_amdgcn_mfma_f32_16x16x32_bf16(ah.v, bl.v, o, 0, 0, 0);
        o = __builtin_amdgcn_mfma_f32_16x16x32_bf16(ah.v, bh.v, o, 0, 0, 0);
      }
      // dt feats f0..7 row-major; B_s -> 8+2s; C_s -> 9+2s
      int p = (r16 < 8) ? r16 : (r16 < 12 ? 8 + 2 * (r16 - 8) : 9 + 2 * (r16 - 12));
#pragma unroll
      for (int q = 0; q < 4; ++q)
        L[RXD + (w * 16 + g * 4 + q) * 20 + p] = o[q];
    }
    __syncthreads();

    // ---- P5: scan, dt-share + batched loads; Y split (b16 x2) into RH/RL ----
    {
      float hsv = 0.f;
#pragma unroll 4
      for (int tb = 0; tb < 16; ++tb) {
        int tme = tb * 4 + ss;                        // this lane's own timestep
        // batched independent loads for this tb (break dependent-load chain)
        const float* xr = &L[RXD + tme * 20];
        float4 xa = *(const float4*)xr;
        float4 xb = *(const float4*)(xr + 4);
        float zg = L[R1 + ds * 67 + tme];             // silu(z) gate (own t)
        float2 bc[4];
        unsigned xu[4];
#pragma unroll
        for (int si = 0; si < 4; ++si) {
          int t = tb * 4 + si;
          bc[si] = *(const float2*)&L[RXD + t * 20 + 8 + 2 * ss];
          xu[si] = Li[RXC + t * 132 + kc_d + (((qs_d + (t & 7)) & 7) << 2)];
        }
        float dot = bd;
        dot = fmaf(xa.x, wdta.x, dot); dot = fmaf(xa.y, wdta.y, dot);
        dot = fmaf(xa.z, wdta.z, dot); dot = fmaf(xa.w, wdta.w, dot);
        dot = fmaf(xb.x, wdtb.x, dot); dot = fmaf(xb.y, wdtb.y, dot);
        dot = fmaf(xb.z, wdtb.z, dot); dot = fmaf(xb.w, wdtb.w, dot);
        float e = __builtin_amdgcn_exp2f(dot * LOG2E);
        float sp = LN2 * __builtin_amdgcn_logf(1.0f + e);
        float dtme = (dot > 20.f) ? dot : sp;         // softplus(own t)
        int wi = tme * 68 + (ds >> 1);                // own-t Y write slot

#define SCANSTEP(SI)                                                          \
        {                                                                     \
          float dtv = qbcast<SI>(dtme);                                       \
          float xcv = unpacksplit(xu[SI]);                                    \
          float dA = __builtin_amdgcn_exp2f(dtv * As2);                       \
          hsv = fmaf(hsv, dA, dtv * xcv * bc[SI].x);                          \
          float y = qsum4(hsv * bc[SI].y);                                    \
          if (SI == ss) {                                                     \
            y = fmaf(xcv, Dd, y);                                             \
            y *= zg;                                                          \
            unsigned yh = bfhi(y);                                            \
            unsigned yl = bfhi(y - __uint_as_float(yh << 16));                \
            Ls[(RH + wi) * 2 + (ds & 1)] = (ushort_t)yh;                      \
            Ls[(RL + wi) * 2 + (ds & 1)] = (ushort_t)yl;                      \
          }                                                                   \
        }
        SCANSTEP(0)
        SCANSTEP(1)
        SCANSTEP(2)
        SCANSTEP(3)
#undef SCANSTEP
      }
    }
    __syncthreads();

    // ---- P6: out_proj out(64x128) = Y @ Wout^T (direct b128 fragments) ----
    {
      f32x4 o[4];
#pragma unroll
      for (int rt = 0; rt < 4; ++rt) o[rt] = (f32x4){0.f, 0.f, 0.f, 0.f};
#pragma unroll
      for (int kc = 0; kc < 4; ++kc) {
        BU bh, bl;
        bh.q = woh[kc];
        bl.q = wol[kc];
#pragma unroll
        for (int rt = 0; rt < 4; ++rt) {
          int base = (rt * 16 + r16) * 68 + kc * 16 + g * 4;
          BU ah, al;
          ah.q = *(const uint4*)&Li[RH + base];
          al.q = *(const uint4*)&Li[RL + base];
          o[rt] = __builtin_amdgcn_mfma_f32_16x16x32_bf16(al.v, bh.v, o[rt], 0, 0, 0);
          o[rt] = __builtin_amdgcn_mfma_f32_16x16x32_bf16(ah.v, bl.v, o[rt], 0, 0, 0);
          o[rt] = __builtin_amdgcn_mfma_f32_16x16x32_bf16(ah.v, bh.v, o[rt], 0, 0, 0);
        }
      }
      float* yout = (float*)(ws + seqoff);   // y f32 overwrites this seq's H
#pragma unroll
      for (int rt = 0; rt < 4; ++rt)
#pragma unroll
        for (int r = 0; r < 4; ++r)
          yout[(rt * 16 + g * 4 + r) * C_ + w * 16 + r16] = o[rt][r];
    }
    __syncthreads();   // RH/RL reuse next sequence
  }
}

// ---------------- K3: transpose (B*N,T,C) -> (B,C,T,N) ----------------------
__global__ __launch_bounds__(256) void k_out_tr(const float* __restrict__ ws_y,
                                                float* __restrict__ out) {
  __shared__ float tile[32 * 132];
  int bx = blockIdx.x;
  int nt = bx & 7, t = (bx >> 3) & 63, b = bx >> 9;
  int n0 = nt * 32;
  int tid = threadIdx.x;
  const float4* y4 = (const float4*)ws_y;
  for (int it = 0; it < 4; ++it) {
    int idx4 = it * 256 + tid;
    int nn = idx4 >> 5, c4 = idx4 & 31;
    float4 v = y4[((b * N_ + n0 + nn) * (long)T_ + t) * (C_ / 4) + c4];
    *(float4*)&tile[nn * 132 + c4 * 4] = v;
  }
  __syncthreads();
  int nn = tid & 31, cg = tid >> 5;
  for (int i = 0; i < 16; ++i) {
    int c = cg * 16 + i;
    out[((b * C_ + c) * (long)T_ + t) * N_ + n0 + nn] = tile[nn * 132 + c];
  }
}

extern "C" void kernel_launch(void* const* d_in, const int* in_sizes, int n_in,
                              void* d_out, int out_size, void* d_ws, size_t ws_size,
                              hipStream_t stream) {
  const float* x    = (const float*)d_in[0];
  const float* gam  = (const float*)d_in[1];
  const float* bet  = (const float*)d_in[2];
  const float* Win  = (const float*)d_in[3];
  const float* cw   = (const float*)d_in[4];
  const float* cb   = (const float*)d_in[5];
  const float* Wx   = (const float*)d_in[6];
  const float* Wdt  = (const float*)d_in[7];
  const float* bdt  = (const float*)d_in[8];
  const float* Alog = (const float*)d_in[9];
  const float* Dp   = (const float*)d_in[10];
  const float* Wout = (const float*)d_in[11];
  float* out = (float*)d_out;
  unsigned* ws = (unsigned*)d_ws;  // 64 MiB: split-H planes -> y f32 in place

  // split-weight storage: ws tail if it fits, else scribble d_out
  const size_t HBYTES = 67108864ull;                      // 64 MiB
  const size_t WBYTES = 131072ull + 65536ull + 8192ull;   // Win + Wout + Wx splits
  char* wtail;
  if (ws_size >= HBYTES + WBYTES) wtail = (char*)d_ws + HBYTES;
  else                            wtail = (char*)d_out;
  ushort_t* wsi = (ushort_t*)wtail;
  ushort_t* wso = (ushort_t*)(wtail + 131072);
  ushort_t* wsx = (ushort_t*)(wtail + 131072 + 65536);

  (void)hipFuncSetAttribute((const void*)k_mamba,
                            hipFuncAttributeMaxDynamicSharedMemorySize,
                            LDSW * 4);

  k_wsplit<<<4, 512, 0, stream>>>(Win, Wout, Wx, wsi, wso, wsx);
  k_ln<<<4096, 256, 0, stream>>>(x, gam, bet, ws);
  k_mamba<<<2048 / NSEQ, 512, LDSW * 4, stream>>>(ws, wsi, wso, wsx, cw, cb,
                                                  Wdt, bdt, Alog, Dp);
  k_out_tr<<<4096, 256, 0, stream>>>((const float*)ws, out);
}